// Round 9
// baseline (959.513 us; speedup 1.0000x reference)
//
#include <hip/hip_runtime.h>
#include <stdint.h>

typedef unsigned long long u64;
typedef unsigned int u32;
typedef float vf2 __attribute__((ext_vector_type(2)));

constexpr int Ccand = 32;   // candidates per row
constexpr int Evoc  = 512;  // vocab size
constexpr int Tgt   = 64;   // target_size

// descending bitonic sort of one f32 per lane across the 64-lane wave
__device__ __forceinline__ void sort64_desc_f32(float& a, int lane) {
    #pragma unroll
    for (int k2 = 2; k2 <= 64; k2 <<= 1) {
        #pragma unroll
        for (int j = k2 >> 1; j > 0; j >>= 1) {
            float o = __shfl_xor(a, j);
            bool lower = (lane & j) == 0;
            bool keepMax = ((lane & k2) == 0) ? lower : !lower;
            bool g = a > o;
            a = (keepMax == g) ? a : o;
        }
    }
}

// descending bitonic sort of one u64 key per lane across the wave
__device__ __forceinline__ void sort64_desc_u64(u64& a, int lane) {
    #pragma unroll
    for (int k2 = 2; k2 <= 64; k2 <<= 1) {
        #pragma unroll
        for (int j = k2 >> 1; j > 0; j >>= 1) {
            u64 o = __shfl_xor(a, j);
            bool lower = (lane & j) == 0;
            bool keepMax = ((lane & k2) == 0) ? lower : !lower;
            bool g = a > o;
            a = (keepMax == g) ? a : o;
        }
    }
}

// One wave (64 lanes) per row. Lane l owns cols {4l..4l+3} and {256+4l..+3}.
__global__ __launch_bounds__(256, 6) void cooc_expand(
    const int* __restrict__ cand_ids,
    const float* __restrict__ cand_scores,
    const float* __restrict__ cooc,
    float* __restrict__ out_ids,
    float* __restrict__ out_scores,
    int B)
{
    const int lane = threadIdx.x & 63;
    const int wid  = threadIdx.x >> 6;
    const int row  = blockIdx.x * 4 + wid;
    __shared__ u64 buf[4][64];   // per-wave 64-slot window (2 KB/block)
    if (row >= B) return;   // never taken (B % 4 == 0); no block barriers used

    // ---- load candidates (lanes 0..31) ----
    int   my_id = -1;
    float my_s  = 0.0f;
    if (lane < Ccand) {
        my_id = cand_ids[(size_t)row * Ccand + lane];
        my_s  = cand_scores[(size_t)row * Ccand + lane];
    }

    // ---- duplicate merge, np.add.at order (ascending i, from 0.0) ----
    int   first = 64;
    float sm    = 0.0f;
    #pragma unroll
    for (int j = 0; j < Ccand; ++j) {
        int   idj = __shfl(my_id, j);   // const lane -> readlane
        float sj  = __shfl(my_s,  j);
        bool match = (idj == my_id);
        if (match && j < first) first = j;
        sm += match ? sj : 0.0f;
    }
    bool alive = (lane < Ccand) && (first == lane);
    u64 aball = __ballot(alive);
    int m = __popcll(aball);

    // ---- rank alive entries by ascending id (alive ids distinct) ----
    int rk = 0;
    #pragma unroll
    for (int j = 0; j < Ccand; ++j) {
        int idj = __shfl(my_id, j);
        bool aj = (aball >> j) & 1ull;
        rk += (aj && idj < my_id) ? 1 : 0;
    }
    int dst = alive ? rk : ((lane < 32) ? (lane + 32) : lane);
    int sorted_id = __builtin_amdgcn_ds_permute(dst << 2, my_id);
    int sorted_sb = __builtin_amdgcn_ds_permute(dst << 2, __float_as_int(sm));

    // ---- accumulation: two-window software pipeline (4 ids/window).
    // While FMAing window A, window B's 8 dwordx4 loads are in flight.
    // readlane -> SGPR base addr; packed v_pk_fma_f32 (bit-exact per
    // component); t>=m: s=0, fma(0,·,acc)==acc bit-exact (acc >= +0).
    vf2 acc2[4];
    acc2[0] = (vf2){0.f, 0.f}; acc2[1] = (vf2){0.f, 0.f};
    acc2[2] = (vf2){0.f, 0.f}; acc2[3] = (vf2){0.f, 0.f};
    u32 maskbits = 0;
    const int l4 = lane << 2;

    int   eA[4], eB[4];
    float sA[4], sB[4];
    float4 A0[4], A1[4], B0[4], B1[4];   // window A regs / window B regs

    #define META(t, ee, ss)                                                   \
        _Pragma("unroll") for (int u = 0; u < 4; ++u) {                       \
            ee[u] = __builtin_amdgcn_readlane(sorted_id, (t) + u) & 511;      \
            ss[u] = ((t) + u < m)                                             \
                ? __int_as_float(__builtin_amdgcn_readlane(sorted_sb, (t) + u)) \
                : 0.0f;                                                       \
        }
    #define LOADW(ee, P, Q)                                                   \
        _Pragma("unroll") for (int u = 0; u < 4; ++u) {                       \
            const float* rp = cooc + ((size_t)ee[u] << 9);                    \
            P[u] = *reinterpret_cast<const float4*>(rp + l4);                 \
            Q[u] = *reinterpret_cast<const float4*>(rp + 256 + l4);           \
        }
    #define FMAW(ss, P, Q)                                                    \
        _Pragma("unroll") for (int u = 0; u < 4; ++u) {                       \
            vf2 sv2; sv2[0] = ss[u]; sv2[1] = ss[u];                          \
            vf2 a0; a0[0] = P[u].x; a0[1] = P[u].y;                           \
            vf2 a1; a1[0] = P[u].z; a1[1] = P[u].w;                           \
            vf2 b0; b0[0] = Q[u].x; b0[1] = Q[u].y;                           \
            vf2 b1; b1[0] = Q[u].z; b1[1] = Q[u].w;                           \
            acc2[0] = __builtin_elementwise_fma(sv2, a0, acc2[0]);            \
            acc2[1] = __builtin_elementwise_fma(sv2, a1, acc2[1]);            \
            acc2[2] = __builtin_elementwise_fma(sv2, b0, acc2[2]);            \
            acc2[3] = __builtin_elementwise_fma(sv2, b1, acc2[3]);            \
        }
    #define MASKW(t, ee)                                                      \
        _Pragma("unroll") for (int u = 0; u < 4; ++u) {                       \
            if (((t) + u < m) && (((ee[u] & 255) >> 2) == lane))              \
                maskbits |= 1u << (((ee[u] >> 8) << 2) | (ee[u] & 3));        \
        }

    // prologue: window A = ids 0..3
    META(0, eA, sA)
    LOADW(eA, A0, A1)
    #pragma unroll 1
    for (int t = 0; t < 32; t += 8) {
        // issue window B (t+4..t+7) while A's loads drain / FMA
        META(t + 4, eB, sB)
        LOADW(eB, B0, B1)
        FMAW(sA, A0, A1)
        MASKW(t, eA)
        // issue next window A (t+8..t+11) while B FMAs
        if (t + 8 < 32) {
            META(t + 8, eA, sA)
            LOADW(eA, A0, A1)
        }
        FMAW(sB, B0, B1)
        MASKW(t + 4, eB)
    }
    #undef META
    #undef LOADW
    #undef FMAW
    #undef MASKW

    // ---- original-layout values; masked -> -1.0 (strictly below all) ----
    float v[8];
    v[0] = acc2[0][0]; v[1] = acc2[0][1]; v[2] = acc2[1][0]; v[3] = acc2[1][1];
    v[4] = acc2[2][0]; v[5] = acc2[2][1]; v[6] = acc2[3][0]; v[7] = acc2[3][1];
    #pragma unroll
    for (int j = 0; j < 8; ++j)
        if ((maskbits >> j) & 1u) v[j] = -1.0f;

    // ---- L32: 32nd largest of per-lane maxima; T >= L32 and every
    // top-32 element (incl. ==T ties) has v >= L32; also S_tot >= 32 ----
    float mx8 = v[0];
    #pragma unroll
    for (int j = 1; j < 8; ++j) mx8 = fmaxf(mx8, v[j]);
    float srt = mx8;
    sort64_desc_f32(srt, lane);
    float L32 = __int_as_float(__builtin_amdgcn_readlane(__float_as_int(srt), 31));

    // ---- survivor count + exclusive scan for global slots ----
    int cnt = 0;
    #pragma unroll
    for (int j = 0; j < 8; ++j) cnt += (v[j] >= L32) ? 1 : 0;
    u32 sincl = (u32)cnt;
    #pragma unroll
    for (int i = 1; i < 64; i <<= 1) {
        u32 t2 = __shfl_up(sincl, i);
        if (lane >= i) sincl += t2;
    }
    int sbase = (int)sincl - cnt;
    int S_tot = __builtin_amdgcn_readlane((int)sincl, 63);

    // ---- chunked scatter + sort + merge-prune over 64-slot windows.
    // Chunk 0 is the whole story for ~99.98% of rows (S_tot <= 64).
    // Keys (valbits<<32 | 511-col) unique; desc u64 order == np stable
    // top-k order (value desc, col asc). ----
    int nchunk = (S_tot + 63) >> 6;   // wave-uniform >= 1
    u64 cur = 0ull;
    #pragma unroll 1
    for (int c = 0; c < nchunk; ++c) {
        const int lo = c << 6;
        // scatter survivors whose slot falls in [lo, lo+64)
        int slot = sbase;
        #pragma unroll
        for (int j = 0; j < 8; ++j) {
            bool s = (v[j] >= L32);
            int  rel = slot - lo;
            if (s && rel >= 0 && rel < 64) {
                int col = (j < 4) ? (l4 + j) : (256 + l4 + (j - 4));
                buf[wid][rel] = ((u64)__float_as_uint(v[j]) << 32) | (u32)(511 - col);
            }
            slot += s ? 1 : 0;
        }
        __threadfence_block();
        u64 nxt = (lo + lane < S_tot) ? buf[wid][lane] : 0ull;
        __threadfence_block();   // reads complete before next chunk's writes
        sort64_desc_u64(nxt, lane);
        if (c == 0) {
            cur = nxt;
        } else {
            u64 o = __shfl_xor(nxt, 63);           // nxt[63-lane]
            cur = (cur >= o) ? cur : o;            // top-64 of 128, bitonic
            #pragma unroll
            for (int j = 32; j > 0; j >>= 1) {     // descending cleanup
                u64 p = __shfl_xor(cur, j);
                bool keepMax = (lane & j) == 0;
                bool g = cur > p;
                cur = (keepMax == g) ? cur : p;
            }
        }
    }
    // lane r now holds rank-r key (r < 32 are the selected top-32)

    // ---- coalesced stores: [orig 32 | selected 32] ----
    int src = (lane >= 32) ? (lane - 32) : 0;
    u64 kk = __shfl(cur, src);
    const size_t ob = (size_t)row * Tgt;
    float oid, osc;
    if (lane < Ccand) {
        oid = (float)my_id;
        osc = my_s;
    } else {
        oid = (float)(int)(511 - (u32)(kk & 511ull));
        osc = __uint_as_float((u32)(kk >> 32));
    }
    out_ids[ob + lane]    = oid;
    out_scores[ob + lane] = osc;
}

extern "C" void kernel_launch(void* const* d_in, const int* in_sizes, int n_in,
                              void* d_out, int out_size, void* d_ws, size_t ws_size,
                              hipStream_t stream) {
    const int*   ids    = (const int*)d_in[0];
    const float* scores = (const float*)d_in[1];
    const float* cooc   = (const float*)d_in[2];
    int B = in_sizes[0] / Ccand;
    float* out_ids    = (float*)d_out;
    float* out_scores = out_ids + (size_t)B * Tgt;
    int blocks = (B + 3) / 4;
    hipLaunchKernelGGL(cooc_expand, dim3(blocks), dim3(256), 0, stream,
                       ids, scores, cooc, out_ids, out_scores, B);
}

// Round 10
// 241.500 us; speedup vs baseline: 3.9731x; 3.9731x over previous
//
#include <hip/hip_runtime.h>
#include <stdint.h>

typedef unsigned long long u64;
typedef unsigned int u32;
typedef float vf2 __attribute__((ext_vector_type(2)));

constexpr int Ccand = 32;   // candidates per row
constexpr int Evoc  = 512;  // vocab size
constexpr int Tgt   = 64;   // target_size

// descending bitonic sort of one f32 per lane across the 64-lane wave
__device__ __forceinline__ void sort64_desc_f32(float& a, int lane) {
    #pragma unroll
    for (int k2 = 2; k2 <= 64; k2 <<= 1) {
        #pragma unroll
        for (int j = k2 >> 1; j > 0; j >>= 1) {
            float o = __shfl_xor(a, j);
            bool lower = (lane & j) == 0;
            bool keepMax = ((lane & k2) == 0) ? lower : !lower;
            bool g = a > o;
            a = (keepMax == g) ? a : o;
        }
    }
}

// descending bitonic sort of one u64 key per lane across the wave
__device__ __forceinline__ void sort64_desc_u64(u64& a, int lane) {
    #pragma unroll
    for (int k2 = 2; k2 <= 64; k2 <<= 1) {
        #pragma unroll
        for (int j = k2 >> 1; j > 0; j >>= 1) {
            u64 o = __shfl_xor(a, j);
            bool lower = (lane & j) == 0;
            bool keepMax = ((lane & k2) == 0) ? lower : !lower;
            bool g = a > o;
            a = (keepMax == g) ? a : o;
        }
    }
}

// One wave (64 lanes) per row. Lane l owns cols {4l..4l+3} and {256+4l..+3}.
// __launch_bounds__(256,4): 128-VGPR cap — the two-window pipeline needs
// ~95 live VGPRs; (256,6)'s 85-cap spilled it to scratch (r9: 4 GB traffic).
__global__ __launch_bounds__(256, 4) void cooc_expand(
    const int* __restrict__ cand_ids,
    const float* __restrict__ cand_scores,
    const float* __restrict__ cooc,
    float* __restrict__ out_ids,
    float* __restrict__ out_scores,
    int B)
{
    const int lane = threadIdx.x & 63;
    const int wid  = threadIdx.x >> 6;
    const int row  = blockIdx.x * 4 + wid;
    __shared__ u64 buf[4][64];   // per-wave 64-slot window (2 KB/block)
    if (row >= B) return;   // never taken (B % 4 == 0); no block barriers used

    // ---- load candidates (lanes 0..31) ----
    int   my_id = -1;
    float my_s  = 0.0f;
    if (lane < Ccand) {
        my_id = cand_ids[(size_t)row * Ccand + lane];
        my_s  = cand_scores[(size_t)row * Ccand + lane];
    }

    // ---- duplicate merge, np.add.at order (ascending i, from 0.0) ----
    int   first = 64;
    float sm    = 0.0f;
    #pragma unroll
    for (int j = 0; j < Ccand; ++j) {
        int   idj = __shfl(my_id, j);   // const lane -> readlane
        float sj  = __shfl(my_s,  j);
        bool match = (idj == my_id);
        if (match && j < first) first = j;
        sm += match ? sj : 0.0f;
    }
    bool alive = (lane < Ccand) && (first == lane);
    u64 aball = __ballot(alive);
    int m = __popcll(aball);

    // ---- rank alive entries by ascending id (alive ids distinct) ----
    int rk = 0;
    #pragma unroll
    for (int j = 0; j < Ccand; ++j) {
        int idj = __shfl(my_id, j);
        bool aj = (aball >> j) & 1ull;
        rk += (aj && idj < my_id) ? 1 : 0;
    }
    int dst = alive ? rk : ((lane < 32) ? (lane + 32) : lane);
    int sorted_id = __builtin_amdgcn_ds_permute(dst << 2, my_id);
    int sorted_sb = __builtin_amdgcn_ds_permute(dst << 2, __float_as_int(sm));

    // ---- accumulation: two-window software pipeline (4 ids/window).
    // While FMAing window A, window B's 8 dwordx4 loads are in flight.
    // readlane -> SGPR base addr; packed v_pk_fma_f32 (bit-exact per
    // component); t>=m: s=0, fma(0,·,acc)==acc bit-exact (acc >= +0).
    vf2 acc2[4];
    acc2[0] = (vf2){0.f, 0.f}; acc2[1] = (vf2){0.f, 0.f};
    acc2[2] = (vf2){0.f, 0.f}; acc2[3] = (vf2){0.f, 0.f};
    u32 maskbits = 0;
    const int l4 = lane << 2;

    int   eA[4], eB[4];
    float sA[4], sB[4];
    float4 A0[4], A1[4], B0[4], B1[4];   // window A regs / window B regs

    #define META(t, ee, ss)                                                   \
        _Pragma("unroll") for (int u = 0; u < 4; ++u) {                       \
            ee[u] = __builtin_amdgcn_readlane(sorted_id, (t) + u) & 511;      \
            ss[u] = ((t) + u < m)                                             \
                ? __int_as_float(__builtin_amdgcn_readlane(sorted_sb, (t) + u)) \
                : 0.0f;                                                       \
        }
    #define LOADW(ee, P, Q)                                                   \
        _Pragma("unroll") for (int u = 0; u < 4; ++u) {                       \
            const float* rp = cooc + ((size_t)ee[u] << 9);                    \
            P[u] = *reinterpret_cast<const float4*>(rp + l4);                 \
            Q[u] = *reinterpret_cast<const float4*>(rp + 256 + l4);           \
        }
    #define FMAW(ss, P, Q)                                                    \
        _Pragma("unroll") for (int u = 0; u < 4; ++u) {                       \
            vf2 sv2; sv2[0] = ss[u]; sv2[1] = ss[u];                          \
            vf2 a0; a0[0] = P[u].x; a0[1] = P[u].y;                           \
            vf2 a1; a1[0] = P[u].z; a1[1] = P[u].w;                           \
            vf2 b0; b0[0] = Q[u].x; b0[1] = Q[u].y;                           \
            vf2 b1; b1[0] = Q[u].z; b1[1] = Q[u].w;                           \
            acc2[0] = __builtin_elementwise_fma(sv2, a0, acc2[0]);            \
            acc2[1] = __builtin_elementwise_fma(sv2, a1, acc2[1]);            \
            acc2[2] = __builtin_elementwise_fma(sv2, b0, acc2[2]);            \
            acc2[3] = __builtin_elementwise_fma(sv2, b1, acc2[3]);            \
        }
    #define MASKW(t, ee)                                                      \
        _Pragma("unroll") for (int u = 0; u < 4; ++u) {                       \
            if (((t) + u < m) && (((ee[u] & 255) >> 2) == lane))              \
                maskbits |= 1u << (((ee[u] >> 8) << 2) | (ee[u] & 3));        \
        }

    // prologue: window A = ids 0..3
    META(0, eA, sA)
    LOADW(eA, A0, A1)
    #pragma unroll 1
    for (int t = 0; t < 32; t += 8) {
        // issue window B (t+4..t+7) while A's loads drain / FMA
        META(t + 4, eB, sB)
        LOADW(eB, B0, B1)
        FMAW(sA, A0, A1)
        MASKW(t, eA)
        // issue next window A (t+8..t+11) while B FMAs
        if (t + 8 < 32) {
            META(t + 8, eA, sA)
            LOADW(eA, A0, A1)
        }
        FMAW(sB, B0, B1)
        MASKW(t + 4, eB)
    }
    #undef META
    #undef LOADW
    #undef FMAW
    #undef MASKW

    // ---- original-layout values; masked -> -1.0 (strictly below all) ----
    float v[8];
    v[0] = acc2[0][0]; v[1] = acc2[0][1]; v[2] = acc2[1][0]; v[3] = acc2[1][1];
    v[4] = acc2[2][0]; v[5] = acc2[2][1]; v[6] = acc2[3][0]; v[7] = acc2[3][1];
    #pragma unroll
    for (int j = 0; j < 8; ++j)
        if ((maskbits >> j) & 1u) v[j] = -1.0f;

    // ---- L32: 32nd largest of per-lane maxima; T >= L32 and every
    // top-32 element (incl. ==T ties) has v >= L32; also S_tot >= 32 ----
    float mx8 = v[0];
    #pragma unroll
    for (int j = 1; j < 8; ++j) mx8 = fmaxf(mx8, v[j]);
    float srt = mx8;
    sort64_desc_f32(srt, lane);
    float L32 = __int_as_float(__builtin_amdgcn_readlane(__float_as_int(srt), 31));

    // ---- survivor count + exclusive scan for global slots ----
    int cnt = 0;
    #pragma unroll
    for (int j = 0; j < 8; ++j) cnt += (v[j] >= L32) ? 1 : 0;
    u32 sincl = (u32)cnt;
    #pragma unroll
    for (int i = 1; i < 64; i <<= 1) {
        u32 t2 = __shfl_up(sincl, i);
        if (lane >= i) sincl += t2;
    }
    int sbase = (int)sincl - cnt;
    int S_tot = __builtin_amdgcn_readlane((int)sincl, 63);

    // ---- chunked scatter + sort + merge-prune over 64-slot windows.
    // Chunk 0 is the whole story for ~99.98% of rows (S_tot <= 64).
    // Keys (valbits<<32 | 511-col) unique; desc u64 order == np stable
    // top-k order (value desc, col asc). ----
    int nchunk = (S_tot + 63) >> 6;   // wave-uniform >= 1
    u64 cur = 0ull;
    #pragma unroll 1
    for (int c = 0; c < nchunk; ++c) {
        const int lo = c << 6;
        // scatter survivors whose slot falls in [lo, lo+64)
        int slot = sbase;
        #pragma unroll
        for (int j = 0; j < 8; ++j) {
            bool s = (v[j] >= L32);
            int  rel = slot - lo;
            if (s && rel >= 0 && rel < 64) {
                int col = (j < 4) ? (l4 + j) : (256 + l4 + (j - 4));
                buf[wid][rel] = ((u64)__float_as_uint(v[j]) << 32) | (u32)(511 - col);
            }
            slot += s ? 1 : 0;
        }
        __threadfence_block();
        u64 nxt = (lo + lane < S_tot) ? buf[wid][lane] : 0ull;
        __threadfence_block();   // reads complete before next chunk's writes
        sort64_desc_u64(nxt, lane);
        if (c == 0) {
            cur = nxt;
        } else {
            u64 o = __shfl_xor(nxt, 63);           // nxt[63-lane]
            cur = (cur >= o) ? cur : o;            // top-64 of 128, bitonic
            #pragma unroll
            for (int j = 32; j > 0; j >>= 1) {     // descending cleanup
                u64 p = __shfl_xor(cur, j);
                bool keepMax = (lane & j) == 0;
                bool g = cur > p;
                cur = (keepMax == g) ? cur : p;
            }
        }
    }
    // lane r now holds rank-r key (r < 32 are the selected top-32)

    // ---- coalesced stores: [orig 32 | selected 32] ----
    int src = (lane >= 32) ? (lane - 32) : 0;
    u64 kk = __shfl(cur, src);
    const size_t ob = (size_t)row * Tgt;
    float oid, osc;
    if (lane < Ccand) {
        oid = (float)my_id;
        osc = my_s;
    } else {
        oid = (float)(int)(511 - (u32)(kk & 511ull));
        osc = __uint_as_float((u32)(kk >> 32));
    }
    out_ids[ob + lane]    = oid;
    out_scores[ob + lane] = osc;
}

extern "C" void kernel_launch(void* const* d_in, const int* in_sizes, int n_in,
                              void* d_out, int out_size, void* d_ws, size_t ws_size,
                              hipStream_t stream) {
    const int*   ids    = (const int*)d_in[0];
    const float* scores = (const float*)d_in[1];
    const float* cooc   = (const float*)d_in[2];
    int B = in_sizes[0] / Ccand;
    float* out_ids    = (float*)d_out;
    float* out_scores = out_ids + (size_t)B * Tgt;
    int blocks = (B + 3) / 4;
    hipLaunchKernelGGL(cooc_expand, dim3(blocks), dim3(256), 0, stream,
                       ids, scores, cooc, out_ids, out_scores, B);
}